// Round 6
// baseline (152.931 us; speedup 1.0000x reference)
//
#include <hip/hip_runtime.h>
#include <hip/hip_bf16.h>

// Problem constants
#define BB 4
#define LL 4096
#define DD 256
#define MM (BB * LL)              // 16384 rows total
#define NSPLIT 8
#define NQB (LL / 128)            // 32 query blocks per batch (BM=128)
#define KPS (LL / NSPLIT)         // 512 keys per split
#define KT 32                     // keys per LDS tile (32 x 512B = 16KB)
#define NKT (KPS / KT)            // 16

typedef short short8 __attribute__((ext_vector_type(8)));   // 8 bf16 (4 VGPRs)
typedef float floatx4 __attribute__((ext_vector_type(4)));

#define SCALE_LOG2E 14.426950408889634f   // INV_TEMP * log2(e)

__device__ __forceinline__ unsigned short f2bf(float f) {
    __hip_bfloat16 h = __float2bfloat16(f);
    union { __hip_bfloat16 h; unsigned short s; } c; c.h = h; return c.s;
}

__device__ __forceinline__ float fast_exp2(float x) {
#if __has_builtin(__builtin_amdgcn_exp2f)
    return __builtin_amdgcn_exp2f(x);
#else
    return exp2f(x);
#endif
}

// Stage 16B/lane global -> LDS (wave-uniform LDS base; lane i -> l + i*16).
__device__ __forceinline__ void stage16(const char* g, char* l, int lane) {
#if __has_builtin(__builtin_amdgcn_global_load_lds)
    __builtin_amdgcn_global_load_lds(
        (const __attribute__((address_space(1))) void*)(g + lane * 16),
        (__attribute__((address_space(3))) void*)l, 16, 0, 0);
#else
    *(short8*)(l + lane * 16) = *(const short8*)(g + lane * 16);
#endif
}

// ---------------------------------------------------------------------------
// Kernel 0: W f32 -> bf16, plain row-major (proj reads W straight from L2).
// Blocks 0..31 convert Wq, 32..63 convert Wk. 8 f32 per thread.
// ---------------------------------------------------------------------------
__global__ __launch_bounds__(256) void cvt_kernel(
    const float* __restrict__ srcq, const float* __restrict__ srck,
    unsigned short* __restrict__ dstq, unsigned short* __restrict__ dstk)
{
    const int which = blockIdx.x >> 5;
    const float* src = which ? srck : srcq;
    unsigned short* dst = which ? dstk : dstq;
    const int t = (blockIdx.x & 31) * 256 + threadIdx.x;
    const float4 v0 = ((const float4*)src)[t * 2];
    const float4 v1 = ((const float4*)src)[t * 2 + 1];
    short8 o;
    o[0] = (short)f2bf(v0.x); o[1] = (short)f2bf(v0.y);
    o[2] = (short)f2bf(v0.z); o[3] = (short)f2bf(v0.w);
    o[4] = (short)f2bf(v1.x); o[5] = (short)f2bf(v1.y);
    o[6] = (short)f2bf(v1.z); o[7] = (short)f2bf(v1.w);
    *(short8*)(dst + (size_t)t * 8) = o;
}

// ---------------------------------------------------------------------------
// Kernel A: one pass (q or k) per block; 512 blocks = (row-block of 64, pass).
// B-frags read DIRECTLY from global W (128KB, L2-resident) -> no staging, no
// main-loop barriers; LDS only holds the 17.4KB transpose buffer (3 blocks/CU,
// VGPR-bound).
// qn = l2norm(lat @ Wq^T)*SCALE_LOG2E, stored FRAGMENT-MAJOR:
//   16B chunk at ((r16*8 + kk)*4 + quad)*16 + (row&15)  (coalesced in attn).
// kn = l2norm(lat @ Wk^T), row-linear with XOR chunk swizzle (c ^= row&7).
// MFMA 16x16x32 bf16; A: m=lane&15,k=quad*8+j; B: n=lane&15,k=quad*8+j;
// C/D: col=lane&15, row=quad*4+reg.
// ---------------------------------------------------------------------------
__global__ __launch_bounds__(256) void proj_norm_kernel(
    const float* __restrict__ latents,
    const __hip_bfloat16* __restrict__ Wq,
    const __hip_bfloat16* __restrict__ Wk,
    __hip_bfloat16* __restrict__ qn,
    __hip_bfloat16* __restrict__ kn)
{
    __shared__ unsigned short tb[64 * 136];   // 17408 B transpose buffer

    const int tid  = threadIdx.x;
    const int wave = tid >> 6;
    const int lane = tid & 63;
    const int n15  = lane & 15;
    const int quad = lane >> 4;

    const int pass  = blockIdx.x & 1;
    const int rbase = (blockIdx.x >> 1) * 64;
    const int m0    = rbase + wave * 16;
    const int r160  = rbase >> 4;

    // A fragments: 16 rows x K=256, f32 loaded, converted in-register
    short8 afrag[8];
    const float* Abase = latents + (size_t)(m0 + n15) * DD + quad * 8;
#pragma unroll
    for (int kk = 0; kk < 8; ++kk) {
        const float4 v0 = *(const float4*)(Abase + kk * 32);
        const float4 v1 = *(const float4*)(Abase + kk * 32 + 4);
        short8 f;
        f[0] = (short)f2bf(v0.x); f[1] = (short)f2bf(v0.y);
        f[2] = (short)f2bf(v0.z); f[3] = (short)f2bf(v0.w);
        f[4] = (short)f2bf(v1.x); f[5] = (short)f2bf(v1.y);
        f[6] = (short)f2bf(v1.z); f[7] = (short)f2bf(v1.w);
        afrag[kk] = f;
    }

    const short* W = (const short*)(pass ? Wk : Wq);

    floatx4 acc[16];
#pragma unroll
    for (int ct = 0; ct < 16; ++ct) acc[ct] = (floatx4){0.f, 0.f, 0.f, 0.f};

#pragma unroll
    for (int ct = 0; ct < 16; ++ct) {
        const short* Brow = W + (size_t)(ct * 16 + n15) * DD + quad * 8;
        floatx4 a = acc[ct];
#pragma unroll
        for (int kk = 0; kk < 8; ++kk) {
            short8 bfr = *(const short8*)(Brow + kk * 32);
            a = __builtin_amdgcn_mfma_f32_16x16x32_bf16(afrag[kk], bfr, a, 0, 0, 0);
        }
        acc[ct] = a;
    }

    // Row norms (rows = quad*4 + r)
    float ss[4] = {0.f, 0.f, 0.f, 0.f};
#pragma unroll
    for (int ct = 0; ct < 16; ++ct)
#pragma unroll
        for (int r = 0; r < 4; ++r) ss[r] += acc[ct][r] * acc[ct][r];
#pragma unroll
    for (int r = 0; r < 4; ++r) {
        ss[r] += __shfl_xor(ss[r], 1, 64);
        ss[r] += __shfl_xor(ss[r], 2, 64);
        ss[r] += __shfl_xor(ss[r], 4, 64);
        ss[r] += __shfl_xor(ss[r], 8, 64);
    }
    float sc[4];
#pragma unroll
    for (int r = 0; r < 4; ++r) {
        sc[r] = 1.f / fmaxf(sqrtf(ss[r]), 1e-12f);
        if (pass == 0) sc[r] *= SCALE_LOG2E;   // fold softmax scale into qn
    }

    // Epilogue: LDS transpose (64 rows x 136-el padded bf16) then coalesced
    // 16B stores. Two halves of 128 cols each.
#pragma unroll
    for (int h = 0; h < 2; ++h) {
        __syncthreads();   // previous tb users done
#pragma unroll
        for (int cth = 0; cth < 8; ++cth) {
            const int ct = h * 8 + cth;
            const int col = cth * 16 + n15;
#pragma unroll
            for (int r = 0; r < 4; ++r) {
                const int rl = wave * 16 + quad * 4 + r;
                tb[rl * 136 + col] = f2bf(acc[ct][r] * sc[r]);
            }
        }
        __syncthreads();
        if (pass == 0) {
#pragma unroll
            for (int j = 0; j < 4; ++j) {
                const int g = tid + j * 256;
                const int n15r = g & 15, q2 = (g >> 4) & 3, kkh = (g >> 6) & 3, r16l = (g >> 8) & 3;
                const int rl = r16l * 16 + n15r;
                short8 v = *(const short8*)(tb + rl * 136 + kkh * 32 + q2 * 8);
                const size_t chunk = (((size_t)(r160 + r16l) * 8 + (h * 4 + kkh)) * 4 + q2) * 16 + n15r;
                *(short8*)((char*)qn + chunk * 16) = v;
            }
        } else {
#pragma unroll
            for (int j = 0; j < 4; ++j) {
                const int g = tid + j * 256;
                const int csl = g & 15, rl = g >> 4;
                const int row = rbase + rl;
                const int ci = csl ^ (row & 7);
                short8 v = *(const short8*)(tb + rl * 136 + ci * 8);
                *(short8*)((char*)kn + (size_t)row * 512 + (h * 16 + csl) * 16) = v;
            }
        }
    }
}

// ---------------------------------------------------------------------------
// Kernel B: flash-style attention sums, double-buffered 32-key LDS tiles.
// Block = 128 q-rows x 512-key split; 1024 blocks, 32KB LDS -> 4-5 blocks/CU.
// One barrier per key-tile: barrier -> issue loads for kt+1 (other buf)
// -> compute kt. e = exp2(acc) (qn pre-scaled; ref's clip(+-50) is a no-op
// since |q.k| <= 1 => |score| <= 10).
// ---------------------------------------------------------------------------
__global__ __launch_bounds__(256) void attn_kernel(
    const __hip_bfloat16* __restrict__ qn,
    const __hip_bfloat16* __restrict__ kn,
    const float* __restrict__ coords,
    float* __restrict__ partials)
{
    __shared__ char lds[2 * 16384];

    const int tid  = threadIdx.x;
    const int wave = tid >> 6;
    const int lane = tid & 63;
    const int n15  = lane & 15;
    const int quad = lane >> 4;
    const int sw   = n15 & 7;

    int bs = blockIdx.x;
    const int qb    = bs % NQB;    bs /= NQB;
    const int split = bs % NSPLIT; bs /= NSPLIT;
    const int b     = bs;

    const int mw = b * LL + qb * 128 + wave * 32;

    const int key_base = b * LL + split * KPS;
    const char* ksrc = (const char*)kn + (size_t)key_base * 512;

    // Pre-stage tile 0 (each wave stages its contiguous 4KB = 8 keys)
    {
        const char* src = ksrc + wave * 4096;
        char* dst = lds + wave * 4096;
#pragma unroll
        for (int j = 0; j < 4; ++j) stage16(src + j * 1024, dst + j * 1024, lane);
    }

    // Q fragments from fragment-major qn: fully coalesced 16B/lane loads
    short8 aq[2][8];
    const int t16 = mw >> 4;
#pragma unroll
    for (int rt = 0; rt < 2; ++rt)
#pragma unroll
        for (int kk = 0; kk < 8; ++kk) {
            const size_t chunk = (((size_t)(t16 + rt) * 8 + kk) * 4 + quad) * 16 + n15;
            aq[rt][kk] = *(const short8*)((const char*)qn + chunk * 16);
        }

    float s0[2][4], s1[2][4], s2[2][4];
#pragma unroll
    for (int rt = 0; rt < 2; ++rt)
#pragma unroll
        for (int r = 0; r < 4; ++r) { s0[rt][r] = 0.f; s1[rt][r] = 0.f; s2[rt][r] = 0.f; }

    for (int kt = 0; kt < NKT; ++kt) {
        __syncthreads();   // own-wave vmcnt drained -> buf (kt&1) visible to all
        if (kt + 1 < NKT) {
            const char* src = ksrc + (size_t)(kt + 1) * KT * 512 + wave * 4096;
            char* dst = lds + ((kt + 1) & 1) * 16384 + wave * 4096;
#pragma unroll
            for (int j = 0; j < 4; ++j) stage16(src + j * 1024, dst + j * 1024, lane);
        }
        const char* buf = lds + (kt & 1) * 16384;

#pragma unroll
        for (int ct = 0; ct < 2; ++ct) {
            const int kidx = key_base + kt * KT + ct * 16 + n15;
            const float2 cc = *(const float2*)(coords + (size_t)kidx * 2);

            floatx4 acc0 = (floatx4){0.f, 0.f, 0.f, 0.f};
            floatx4 acc1 = (floatx4){0.f, 0.f, 0.f, 0.f};
            const char* lbase = buf + (ct * 16 + n15) * 512;
#pragma unroll
            for (int kk = 0; kk < 8; ++kk) {
                const int chunk = (4 * kk + quad) ^ sw;
                short8 bfr = *(const short8*)(lbase + chunk * 16);
                acc0 = __builtin_amdgcn_mfma_f32_16x16x32_bf16(aq[0][kk], bfr, acc0, 0, 0, 0);
                acc1 = __builtin_amdgcn_mfma_f32_16x16x32_bf16(aq[1][kk], bfr, acc1, 0, 0, 0);
            }
#pragma unroll
            for (int r = 0; r < 4; ++r) {
                const float e0 = fast_exp2(acc0[r]);
                const float e1 = fast_exp2(acc1[r]);
                s0[0][r] += e0;
                s1[0][r] = fmaf(cc.x, e0, s1[0][r]);
                s2[0][r] = fmaf(cc.y, e0, s2[0][r]);
                s0[1][r] += e1;
                s1[1][r] = fmaf(cc.x, e1, s1[1][r]);
                s2[1][r] = fmaf(cc.y, e1, s2[1][r]);
            }
        }
    }

    // Reduce across the 16 lanes of each quad
#pragma unroll
    for (int rt = 0; rt < 2; ++rt)
#pragma unroll
        for (int r = 0; r < 4; ++r)
#pragma unroll
            for (int mask = 1; mask <= 8; mask <<= 1) {
                s0[rt][r] += __shfl_xor(s0[rt][r], mask, 64);
                s1[rt][r] += __shfl_xor(s1[rt][r], mask, 64);
                s2[rt][r] += __shfl_xor(s2[rt][r], mask, 64);
            }

    if (n15 == 0) {
#pragma unroll
        for (int rt = 0; rt < 2; ++rt)
#pragma unroll
            for (int r = 0; r < 4; ++r) {
                const int m = mw + rt * 16 + quad * 4 + r;
                float* p = partials + ((size_t)split * MM + m) * 4;
                p[0] = s0[rt][r];
                p[1] = s1[rt][r];
                p[2] = s2[rt][r];
            }
    }
}

// ---------------------------------------------------------------------------
// Kernel C: combine splits, alpha blend, emit new_coords + displacement (f32).
// ---------------------------------------------------------------------------
__global__ __launch_bounds__(256) void finish_kernel(
    const float* __restrict__ partials,
    const float* __restrict__ coords,
    const float* __restrict__ alpha_raw,
    float* __restrict__ out)
{
    const int m = blockIdx.x * 256 + threadIdx.x;

    const float alpha = 1.f / (1.f + __expf(-alpha_raw[0]));

    float s0 = 0.f, s1 = 0.f, s2 = 0.f;
#pragma unroll
    for (int s = 0; s < NSPLIT; ++s) {
        const float4 v = *(const float4*)(partials + ((size_t)s * MM + m) * 4);
        s0 += v.x; s1 += v.y; s2 += v.z;
    }

    const float cx = coords[m * 2];
    const float cy = coords[m * 2 + 1];
    const float inv = 1.f / s0;
    const float nx = alpha * (s1 * inv) + (1.f - alpha) * cx;
    const float ny = alpha * (s2 * inv) + (1.f - alpha) * cy;

    out[m * 2]     = nx;
    out[m * 2 + 1] = ny;
    out[2 * MM + m * 2]     = nx - cx;
    out[2 * MM + m * 2 + 1] = ny - cy;
}

extern "C" void kernel_launch(void* const* d_in, const int* in_sizes, int n_in,
                              void* d_out, int out_size, void* d_ws, size_t ws_size,
                              hipStream_t stream) {
    const float* latents   = (const float*)d_in[0];
    const float* coords    = (const float*)d_in[1];
    const float* Wq        = (const float*)d_in[2];
    const float* Wk        = (const float*)d_in[3];
    const float* alpha_raw = (const float*)d_in[4];
    // d_in[5] = layer_idx: selects weight set only; provided W's are the
    // pred_idx=1 params, so unused.

    char* ws = (char*)d_ws;
    __hip_bfloat16* qn   = (__hip_bfloat16*)ws;                                  // 8 MB (fragment-major)
    __hip_bfloat16* kn   = (__hip_bfloat16*)(ws + (size_t)8 * 1024 * 1024);      // 8 MB (swizzled rows)
    __hip_bfloat16* wq_b = (__hip_bfloat16*)(ws + (size_t)16 * 1024 * 1024);     // 128 KB (plain)
    __hip_bfloat16* wk_b = (__hip_bfloat16*)(ws + (size_t)16 * 1024 * 1024 + 131072);
    float* partials      = (float*)(ws + (size_t)16 * 1024 * 1024 + 262144);     // 2 MB

    float* out = (float*)d_out;

    cvt_kernel<<<64, 256, 0, stream>>>(Wq, Wk, (unsigned short*)wq_b, (unsigned short*)wk_b);
    proj_norm_kernel<<<512, 256, 0, stream>>>(latents, wq_b, wk_b, qn, kn);
    attn_kernel<<<BB * NQB * NSPLIT, 256, 0, stream>>>(qn, kn, coords, partials);
    finish_kernel<<<MM / 256, 256, 0, stream>>>(partials, coords, alpha_raw, out);
}

// Round 7
// 121.231 us; speedup vs baseline: 1.2615x; 1.2615x over previous
//
#include <hip/hip_runtime.h>
#include <hip/hip_bf16.h>

// Problem constants
#define BB 4
#define LL 4096
#define DD 256
#define MM (BB * LL)              // 16384 rows total
#define NSPLIT 8
#define BM 256                    // query rows per attn block
#define NQB (LL / BM)             // 16 query blocks per batch
#define KPS (LL / NSPLIT)         // 512 keys per split
#define KT 64                     // keys per LDS tile (64 x 512B = 32KB)
#define NKT (KPS / KT)            // 8

typedef short short8 __attribute__((ext_vector_type(8)));   // 8 bf16 (4 VGPRs)
typedef float floatx4 __attribute__((ext_vector_type(4)));

#define SCALE_LOG2E 14.426950408889634f   // INV_TEMP * log2(e)

__device__ __forceinline__ unsigned short f2bf(float f) {
    __hip_bfloat16 h = __float2bfloat16(f);
    union { __hip_bfloat16 h; unsigned short s; } c; c.h = h; return c.s;
}

__device__ __forceinline__ float fast_exp2(float x) {
#if __has_builtin(__builtin_amdgcn_exp2f)
    return __builtin_amdgcn_exp2f(x);
#else
    return exp2f(x);
#endif
}

// Stage 16B/lane global -> LDS (wave-uniform LDS base; lane i -> l + i*16).
__device__ __forceinline__ void stage16(const char* g, char* l, int lane) {
#if __has_builtin(__builtin_amdgcn_global_load_lds)
    __builtin_amdgcn_global_load_lds(
        (const __attribute__((address_space(1))) void*)(g + lane * 16),
        (__attribute__((address_space(3))) void*)l, 16, 0, 0);
#else
    *(short8*)(l + lane * 16) = *(const short8*)(g + lane * 16);
#endif
}

// ---------------------------------------------------------------------------
// Kernel 0: W f32 -> bf16 with XOR chunk swizzle (chunk c of row r stored at
// c ^ (r&7)). Blocks 0..31 convert Wq, 32..63 convert Wk.
// ---------------------------------------------------------------------------
__global__ __launch_bounds__(256) void cvt_swz_kernel(
    const float* __restrict__ srcq, const float* __restrict__ srck,
    unsigned short* __restrict__ dstq, unsigned short* __restrict__ dstk)
{
    const int which = blockIdx.x >> 5;
    const float* src = which ? srck : srcq;
    unsigned short* dst = which ? dstk : dstq;
    const int t = (blockIdx.x & 31) * 256 + threadIdx.x;
    const int r = t >> 5, c = t & 31;
    const float4 v0 = ((const float4*)src)[t * 2];
    const float4 v1 = ((const float4*)src)[t * 2 + 1];
    short8 o;
    o[0] = (short)f2bf(v0.x); o[1] = (short)f2bf(v0.y);
    o[2] = (short)f2bf(v0.z); o[3] = (short)f2bf(v0.w);
    o[4] = (short)f2bf(v1.x); o[5] = (short)f2bf(v1.y);
    o[6] = (short)f2bf(v1.z); o[7] = (short)f2bf(v1.w);
    const int cs = c ^ (r & 7);
    *(short8*)(dst + (size_t)r * DD + cs * 8) = o;
}

// ---------------------------------------------------------------------------
// Kernel A: one pass (q or k) per block; 512 blocks = (row-block of 64, pass).
// W staged through LDS (double-buffered, global_load_lds) from pre-swizzled W.
// qn = l2norm(lat @ Wq^T)*SCALE_LOG2E, stored FRAGMENT-MAJOR:
//   16B chunk at ((r16*8 + kk)*4 + quad)*16 + (row&15)  (coalesced in attn).
// kn = l2norm(lat @ Wk^T), row-linear with XOR chunk swizzle (c ^= row&7).
// MFMA 16x16x32 bf16; A: m=lane&15,k=quad*8+j; B: n=lane&15,k=quad*8+j;
// C/D: col=lane&15, row=quad*4+reg.
// ---------------------------------------------------------------------------
__global__ __launch_bounds__(256) void proj_norm_kernel(
    const float* __restrict__ latents,
    const __hip_bfloat16* __restrict__ Wq,
    const __hip_bfloat16* __restrict__ Wk,
    __hip_bfloat16* __restrict__ qn,
    __hip_bfloat16* __restrict__ kn)
{
    __shared__ char lds[65536];   // 2 x 32KB W double-buffer; reused for transpose

    const int tid  = threadIdx.x;
    const int wave = tid >> 6;
    const int lane = tid & 63;
    const int n15  = lane & 15;
    const int quad = lane >> 4;
    const int sw   = n15 & 7;

    const int pass  = blockIdx.x & 1;
    const int rbase = (blockIdx.x >> 1) * 64;
    const int m0    = rbase + wave * 16;
    const int r160  = rbase >> 4;

    // A fragments: 16 rows x K=256, f32 loaded, converted in-register
    short8 afrag[8];
    const float* Abase = latents + (size_t)(m0 + n15) * DD + quad * 8;
#pragma unroll
    for (int kk = 0; kk < 8; ++kk) {
        const float4 v0 = *(const float4*)(Abase + kk * 32);
        const float4 v1 = *(const float4*)(Abase + kk * 32 + 4);
        short8 f;
        f[0] = (short)f2bf(v0.x); f[1] = (short)f2bf(v0.y);
        f[2] = (short)f2bf(v0.z); f[3] = (short)f2bf(v0.w);
        f[4] = (short)f2bf(v1.x); f[5] = (short)f2bf(v1.y);
        f[6] = (short)f2bf(v1.z); f[7] = (short)f2bf(v1.w);
        afrag[kk] = f;
    }

    const char* W = (const char*)(pass ? Wk : Wq);

    floatx4 acc[16];
#pragma unroll
    for (int ct = 0; ct < 16; ++ct) acc[ct] = (floatx4){0.f, 0.f, 0.f, 0.f};

    // Pre-stage round 0 into buf 0
    {
        const char* src = W + wave * 8192;
        char* dst = lds + wave * 8192;
#pragma unroll
        for (int j = 0; j < 8; ++j) stage16(src + j * 1024, dst + j * 1024, lane);
    }

    for (int round = 0; round < 4; ++round) {
        __syncthreads();    // own-wave vmcnt drained -> buf (round&1) ready
        if (round + 1 < 4) {
            const char* src = W + (size_t)(round + 1) * 32768 + wave * 8192;
            char* dst = lds + ((round + 1) & 1) * 32768 + wave * 8192;
#pragma unroll
            for (int j = 0; j < 8; ++j) stage16(src + j * 1024, dst + j * 1024, lane);
        }
        const char* buf = lds + (round & 1) * 32768;
#pragma unroll
        for (int jt = 0; jt < 4; ++jt) {
            const int ct = round * 4 + jt;
            const char* lbase = buf + (jt * 16 + n15) * 512;
            floatx4 a = acc[ct];
#pragma unroll
            for (int kk = 0; kk < 8; ++kk) {
                const int chunk = (4 * kk + quad) ^ sw;
                short8 bfr = *(const short8*)(lbase + chunk * 16);
                a = __builtin_amdgcn_mfma_f32_16x16x32_bf16(afrag[kk], bfr, a, 0, 0, 0);
            }
            acc[ct] = a;
        }
    }

    // Row norms (rows = quad*4 + r)
    float ss[4] = {0.f, 0.f, 0.f, 0.f};
#pragma unroll
    for (int ct = 0; ct < 16; ++ct)
#pragma unroll
        for (int r = 0; r < 4; ++r) ss[r] += acc[ct][r] * acc[ct][r];
#pragma unroll
    for (int r = 0; r < 4; ++r) {
        ss[r] += __shfl_xor(ss[r], 1, 64);
        ss[r] += __shfl_xor(ss[r], 2, 64);
        ss[r] += __shfl_xor(ss[r], 4, 64);
        ss[r] += __shfl_xor(ss[r], 8, 64);
    }
    float sc[4];
#pragma unroll
    for (int r = 0; r < 4; ++r) {
        sc[r] = 1.f / fmaxf(sqrtf(ss[r]), 1e-12f);
        if (pass == 0) sc[r] *= SCALE_LOG2E;   // fold softmax scale into qn
    }

    // Epilogue: LDS transpose (64 rows x 136-el padded bf16) then coalesced
    // 16B stores. Two halves of 128 cols each.
    unsigned short* tb = (unsigned short*)lds;
#pragma unroll
    for (int h = 0; h < 2; ++h) {
        __syncthreads();   // previous lds users done
#pragma unroll
        for (int cth = 0; cth < 8; ++cth) {
            const int ct = h * 8 + cth;
            const int col = cth * 16 + n15;
#pragma unroll
            for (int r = 0; r < 4; ++r) {
                const int rl = wave * 16 + quad * 4 + r;
                tb[rl * 136 + col] = f2bf(acc[ct][r] * sc[r]);
            }
        }
        __syncthreads();
        if (pass == 0) {
#pragma unroll
            for (int j = 0; j < 4; ++j) {
                const int g = tid + j * 256;
                const int n15r = g & 15, q2 = (g >> 4) & 3, kkh = (g >> 6) & 3, r16l = (g >> 8) & 3;
                const int rl = r16l * 16 + n15r;
                short8 v = *(const short8*)(tb + rl * 136 + kkh * 32 + q2 * 8);
                const size_t chunk = (((size_t)(r160 + r16l) * 8 + (h * 4 + kkh)) * 4 + q2) * 16 + n15r;
                *(short8*)((char*)qn + chunk * 16) = v;
            }
        } else {
#pragma unroll
            for (int j = 0; j < 4; ++j) {
                const int g = tid + j * 256;
                const int csl = g & 15, rl = g >> 4;
                const int row = rbase + rl;
                const int ci = csl ^ (row & 7);
                short8 v = *(const short8*)(tb + rl * 136 + ci * 8);
                *(short8*)((char*)kn + (size_t)row * 512 + (h * 16 + csl) * 16) = v;
            }
        }
    }
}

// ---------------------------------------------------------------------------
// Kernel B: flash-style attention sums. BM=256 q-rows (8 waves x 32 rows),
// 512-key split, KT=64 double-buffered (2x32KB LDS). 512 blocks = 2/CU.
// One barrier per key-tile; 64 MFMA/wave between barriers (2x R6's work per
// barrier, half the staging bytes per MFMA). e = exp2(acc) (qn pre-scaled;
// ref's clip(+-50) is a no-op since |q.k| <= 1 => |score| <= 10).
// ---------------------------------------------------------------------------
__global__ __launch_bounds__(512) void attn_kernel(
    const __hip_bfloat16* __restrict__ qn,
    const __hip_bfloat16* __restrict__ kn,
    const float* __restrict__ coords,
    float* __restrict__ partials)
{
    __shared__ char lds[2 * 32768];

    const int tid  = threadIdx.x;
    const int wave = tid >> 6;
    const int lane = tid & 63;
    const int n15  = lane & 15;
    const int quad = lane >> 4;
    const int sw   = n15 & 7;

    int bs = blockIdx.x;
    const int qb    = bs % NQB;    bs /= NQB;   // consecutive blocks share (b,split) kn slice
    const int split = bs % NSPLIT; bs /= NSPLIT;
    const int b     = bs;

    const int mw = b * LL + qb * BM + wave * 32;

    const int key_base = b * LL + split * KPS;
    const char* ksrc = (const char*)kn + (size_t)key_base * 512;

    // Pre-stage tile 0 (each of 8 waves stages its contiguous 4KB = 8 keys)
    {
        const char* src = ksrc + wave * 4096;
        char* dst = lds + wave * 4096;
#pragma unroll
        for (int j = 0; j < 4; ++j) stage16(src + j * 1024, dst + j * 1024, lane);
    }

    // Q fragments from fragment-major qn: fully coalesced 16B/lane loads
    short8 aq[2][8];
    const int t16 = mw >> 4;
#pragma unroll
    for (int rt = 0; rt < 2; ++rt)
#pragma unroll
        for (int kk = 0; kk < 8; ++kk) {
            const size_t chunk = (((size_t)(t16 + rt) * 8 + kk) * 4 + quad) * 16 + n15;
            aq[rt][kk] = *(const short8*)((const char*)qn + chunk * 16);
        }

    float s0[2][4], s1[2][4], s2[2][4];
#pragma unroll
    for (int rt = 0; rt < 2; ++rt)
#pragma unroll
        for (int r = 0; r < 4; ++r) { s0[rt][r] = 0.f; s1[rt][r] = 0.f; s2[rt][r] = 0.f; }

    for (int kt = 0; kt < NKT; ++kt) {
        __syncthreads();   // own-wave vmcnt drained -> buf (kt&1) visible to all
        if (kt + 1 < NKT) {
            const char* src = ksrc + (size_t)(kt + 1) * KT * 512 + wave * 4096;
            char* dst = lds + ((kt + 1) & 1) * 32768 + wave * 4096;
#pragma unroll
            for (int j = 0; j < 4; ++j) stage16(src + j * 1024, dst + j * 1024, lane);
        }
        const char* buf = lds + (kt & 1) * 32768;

#pragma unroll
        for (int ct = 0; ct < 4; ++ct) {
            const int kidx = key_base + kt * KT + ct * 16 + n15;
            const float2 cc = *(const float2*)(coords + (size_t)kidx * 2);

            floatx4 acc0 = (floatx4){0.f, 0.f, 0.f, 0.f};
            floatx4 acc1 = (floatx4){0.f, 0.f, 0.f, 0.f};
            const char* lbase = buf + (ct * 16 + n15) * 512;
#pragma unroll
            for (int kk = 0; kk < 8; ++kk) {
                const int chunk = (4 * kk + quad) ^ sw;
                short8 bfr = *(const short8*)(lbase + chunk * 16);
                acc0 = __builtin_amdgcn_mfma_f32_16x16x32_bf16(aq[0][kk], bfr, acc0, 0, 0, 0);
                acc1 = __builtin_amdgcn_mfma_f32_16x16x32_bf16(aq[1][kk], bfr, acc1, 0, 0, 0);
            }
#pragma unroll
            for (int r = 0; r < 4; ++r) {
                const float e0 = fast_exp2(acc0[r]);
                const float e1 = fast_exp2(acc1[r]);
                s0[0][r] += e0;
                s1[0][r] = fmaf(cc.x, e0, s1[0][r]);
                s2[0][r] = fmaf(cc.y, e0, s2[0][r]);
                s0[1][r] += e1;
                s1[1][r] = fmaf(cc.x, e1, s1[1][r]);
                s2[1][r] = fmaf(cc.y, e1, s2[1][r]);
            }
        }
    }

    // Reduce across the 16 lanes of each quad
#pragma unroll
    for (int rt = 0; rt < 2; ++rt)
#pragma unroll
        for (int r = 0; r < 4; ++r)
#pragma unroll
            for (int mask = 1; mask <= 8; mask <<= 1) {
                s0[rt][r] += __shfl_xor(s0[rt][r], mask, 64);
                s1[rt][r] += __shfl_xor(s1[rt][r], mask, 64);
                s2[rt][r] += __shfl_xor(s2[rt][r], mask, 64);
            }

    if (n15 == 0) {
#pragma unroll
        for (int rt = 0; rt < 2; ++rt)
#pragma unroll
            for (int r = 0; r < 4; ++r) {
                const int m = mw + rt * 16 + quad * 4 + r;
                float* p = partials + ((size_t)split * MM + m) * 4;
                p[0] = s0[rt][r];
                p[1] = s1[rt][r];
                p[2] = s2[rt][r];
            }
    }
}

// ---------------------------------------------------------------------------
// Kernel C: combine splits, alpha blend, emit new_coords + displacement (f32).
// ---------------------------------------------------------------------------
__global__ __launch_bounds__(256) void finish_kernel(
    const float* __restrict__ partials,
    const float* __restrict__ coords,
    const float* __restrict__ alpha_raw,
    float* __restrict__ out)
{
    const int m = blockIdx.x * 256 + threadIdx.x;

    const float alpha = 1.f / (1.f + __expf(-alpha_raw[0]));

    float s0 = 0.f, s1 = 0.f, s2 = 0.f;
#pragma unroll
    for (int s = 0; s < NSPLIT; ++s) {
        const float4 v = *(const float4*)(partials + ((size_t)s * MM + m) * 4);
        s0 += v.x; s1 += v.y; s2 += v.z;
    }

    const float cx = coords[m * 2];
    const float cy = coords[m * 2 + 1];
    const float inv = 1.f / s0;
    const float nx = alpha * (s1 * inv) + (1.f - alpha) * cx;
    const float ny = alpha * (s2 * inv) + (1.f - alpha) * cy;

    out[m * 2]     = nx;
    out[m * 2 + 1] = ny;
    out[2 * MM + m * 2]     = nx - cx;
    out[2 * MM + m * 2 + 1] = ny - cy;
}

extern "C" void kernel_launch(void* const* d_in, const int* in_sizes, int n_in,
                              void* d_out, int out_size, void* d_ws, size_t ws_size,
                              hipStream_t stream) {
    const float* latents   = (const float*)d_in[0];
    const float* coords    = (const float*)d_in[1];
    const float* Wq        = (const float*)d_in[2];
    const float* Wk        = (const float*)d_in[3];
    const float* alpha_raw = (const float*)d_in[4];
    // d_in[5] = layer_idx: selects weight set only; provided W's are the
    // pred_idx=1 params, so unused.

    char* ws = (char*)d_ws;
    __hip_bfloat16* qn   = (__hip_bfloat16*)ws;                                  // 8 MB (fragment-major)
    __hip_bfloat16* kn   = (__hip_bfloat16*)(ws + (size_t)8 * 1024 * 1024);      // 8 MB (swizzled rows)
    __hip_bfloat16* wq_b = (__hip_bfloat16*)(ws + (size_t)16 * 1024 * 1024);     // 128 KB (swizzled)
    __hip_bfloat16* wk_b = (__hip_bfloat16*)(ws + (size_t)16 * 1024 * 1024 + 131072);
    float* partials      = (float*)(ws + (size_t)16 * 1024 * 1024 + 262144);     // 2 MB

    float* out = (float*)d_out;

    cvt_swz_kernel<<<64, 256, 0, stream>>>(Wq, Wk, (unsigned short*)wq_b, (unsigned short*)wk_b);
    proj_norm_kernel<<<512, 256, 0, stream>>>(latents, wq_b, wk_b, qn, kn);
    attn_kernel<<<BB * NQB * NSPLIT, 512, 0, stream>>>(qn, kn, coords, partials);
    finish_kernel<<<MM / 256, 256, 0, stream>>>(partials, coords, alpha_raw, out);
}